// Round 2
// baseline (233.422 us; speedup 1.0000x reference)
//
#include <hip/hip_runtime.h>

// ImportanceAggregator pipeline:
//   K0 convert_all  : feat fp32 -> featb bf16  AND  W -> wtp bf16, kb-major.
//   K1 pool_slices  : XCD-sliced gather. Old pool_b was at the per-XCD
//                     L2 compulsory-fill floor (FETCH 174.8 MB = 8 x 22.1 MB =
//                     8 x unique-rows-touched x 512 B, R2-R8). Fix: block
//                     (chunk*8 + s) handles only dims [s*32, s*32+32) -> with
//                     round-robin blockIdx%8 -> XCD dispatch, XCD s keeps a
//                     3.2 MB slice of featb L2-RESIDENT (< 4 MB) and all its
//                     gathers hit L2. Lane layout: kg = lane>>3 (k-group),
//                     dl = lane&7 (dim-quad); one node = 2 gathers (8 rows x
//                     64 B = 512 B/instr, same coalescing as pool_b) + 3-step
//                     shfl_xor butterfly over k-groups. nt-hints on nbr/iw/agg
//                     streams protect the resident slice from eviction.
//                     (R1 fix: nt builtins need ext_vector types, not the
//                     HIP_vector_type ushort4 struct.)
//   K2 gemm_ln      : out = LN(agg @ W + b)*gamma + beta via MFMA 16x16x32,
//                     LDS-staged B double buffer (unchanged, proven).
// Lessons pinned: no 64-thread blocks (R6); no hoisted runtime-indexed arrays
// (R4 alloca->LDS); float4 epilogue beats segment stores (R3 vs R5);
// launch_bounds min-waves is a VGPR cap -> spill (R7); natural alloc (R8).
// agg bf16 rows live in d_out at 1 KB stride; gemm_ln blocks read only their
// own 64 rows then overwrite exactly those rows -> no cross-block hazard.

#define NN   50000
#define KNB  16
#define D    256
#define WSTR 272   // epilogue slab stride (floats): 272%32=16 -> 2-way alias = free
#define NPB  32    // nodes per chunk in pool_slices (8 per wave)

typedef __attribute__((ext_vector_type(8))) short short8;   // 8 x bf16 (4 VGPRs)
typedef __attribute__((ext_vector_type(4))) float f32x4;
typedef __attribute__((ext_vector_type(4))) unsigned short us4;  // nt-capable

static __device__ __forceinline__ unsigned short f2bf(float x) {
    unsigned int u = __float_as_uint(x);
    return (unsigned short)((u + 0x7FFFu + ((u >> 16) & 1u)) >> 16);  // RNE
}
static __device__ __forceinline__ float bf2f(unsigned short h) {
    return __uint_as_float((unsigned int)h << 16);
}

// ---------------- K0: both conversions in one dispatch --------------------
// blocks [0,nfb): feat fp32 -> bf16 (8 elem/thread).
// blocks [nfb,nfb+32): W -> bf16 packed kb-major: frag g=(kb*16+c)*64+lane
//   holds B[k = kb*32 + (lane>>4)*8 + j][n = c*16 + (lane&15)], so chunk kb
//   is one contiguous 16 KB block (LDS-stageable with linear copies).
__global__ __launch_bounds__(256) void convert_all(const float* __restrict__ feat,
                                                   const float* __restrict__ Wm,
                                                   unsigned short* __restrict__ featb,
                                                   unsigned short* __restrict__ wtp,
                                                   int nfb) {
    if ((int)blockIdx.x < nfb) {
        const size_t g = (size_t)blockIdx.x * 256 + threadIdx.x;
        const float4 a = *(const float4*)(feat + g * 8);
        const float4 b = *(const float4*)(feat + g * 8 + 4);
        short8 o;
        o[0] = (short)f2bf(a.x); o[1] = (short)f2bf(a.y);
        o[2] = (short)f2bf(a.z); o[3] = (short)f2bf(a.w);
        o[4] = (short)f2bf(b.x); o[5] = (short)f2bf(b.y);
        o[6] = (short)f2bf(b.z); o[7] = (short)f2bf(b.w);
        *(short8*)(featb + g * 8) = o;
    } else {
        const int g    = (blockIdx.x - nfb) * 256 + threadIdx.x;    // 0..8191
        const int lane = g & 63;
        const int c    = (g >> 6) & 15;
        const int kb   = g >> 10;
        const int n    = c * 16 + (lane & 15);
        const int k0   = kb * 32 + (lane >> 4) * 8;
        short8 v;
        #pragma unroll
        for (int j = 0; j < 8; ++j) v[j] = (short)f2bf(Wm[(size_t)(k0 + j) * D + n]);
        *(short8*)(wtp + (size_t)g * 8) = v;
    }
}

// ---------------- K1: XCD-sliced weighted neighbor pooling ----------------
// Grid = 8 * ceil(NN/NPB); slice s = blockIdx&7 -> XCD s (round-robin).
// Each wave: 8 nodes sequentially; per node 2 gathers (k=kg, k=kg+8) of
// 64 B each at dims [s*32 + dl*4), then butterfly-sum over k-groups.
__global__ __launch_bounds__(256, 8) void pool_slices(
        const unsigned short* __restrict__ featb,
        const int*   __restrict__ nbr,
        const float* __restrict__ iw,
        unsigned short* __restrict__ aggb) {
    const int t     = threadIdx.x;
    const int lane  = t & 63;
    const int wq    = t >> 6;
    const int s     = blockIdx.x & 7;            // slice == XCD (heuristic only)
    const int chunk = blockIdx.x >> 3;
    const int dl    = lane & 7;                  // dim-quad within 32-dim slice
    const int kg    = lane >> 3;                 // k-group 0..7
    const int dbase = s * 32 + dl * 4;           // short offset within a row

    const int n0 = chunk * NPB + wq * (NPB / 4); // 8 nodes per wave
    #pragma unroll 1
    for (int j = 0; j < NPB / 4; ++j) {
        const int n = n0 + j;
        if (n >= NN) break;                      // wave-uniform
        const size_t base = (size_t)n * KNB;
        const int   i0 = __builtin_nontemporal_load(nbr + base + kg);
        const int   i1 = __builtin_nontemporal_load(nbr + base + 8 + kg);
        const float w0 = __builtin_nontemporal_load(iw  + base + kg);
        const float w1 = __builtin_nontemporal_load(iw  + base + 8 + kg);
        // wsum over all 16 k: butterfly over k-group bits (lane bits 3,4,5)
        float ws = w0 + w1;
        ws += __shfl_xor(ws, 8,  64);
        ws += __shfl_xor(ws, 16, 64);
        ws += __shfl_xor(ws, 32, 64);
        const bool  zsum = (ws == 0.f);
        const float inv  = zsum ? (1.f / KNB) : (1.f / ws);
        const float f0   = zsum ? inv : (w0 * inv);
        const float f1   = zsum ? inv : (w1 * inv);
        // 64 B gathers: 8 lanes (dl) x us4 per row, L2-resident slice
        const us4 u0 = *(const us4*)(featb + (size_t)i0 * D + dbase);
        const us4 u1 = *(const us4*)(featb + (size_t)i1 * D + dbase);
        float4 p;
        p.x = f0 * bf2f(u0[0]) + f1 * bf2f(u1[0]);
        p.y = f0 * bf2f(u0[1]) + f1 * bf2f(u1[1]);
        p.z = f0 * bf2f(u0[2]) + f1 * bf2f(u1[2]);
        p.w = f0 * bf2f(u0[3]) + f1 * bf2f(u1[3]);
        #pragma unroll
        for (int off = 8; off < 64; off <<= 1) { // sum over k-groups
            p.x += __shfl_xor(p.x, off, 64);
            p.y += __shfl_xor(p.y, off, 64);
            p.z += __shfl_xor(p.z, off, 64);
            p.w += __shfl_xor(p.w, off, 64);
        }
        if (kg == 0) {                           // lanes 0..7: one full 64 B line
            us4 o;
            o[0] = f2bf(p.x); o[1] = f2bf(p.y); o[2] = f2bf(p.z); o[3] = f2bf(p.w);
            __builtin_nontemporal_store(o,
                (us4*)(aggb + (size_t)n * 512 + dbase));
        }
    }
}

// Fallback (ws too small for featb): fp32 gathers, one wave per node.
__global__ __launch_bounds__(256, 8) void pool_f(const float* __restrict__ feat,
                                                 const int*   __restrict__ nbr,
                                                 const float* __restrict__ iw,
                                                 unsigned short* __restrict__ aggb) {
    const int  t    = threadIdx.x;
    const int  lane = t & 63;
    const int  wq   = t >> 6;
    const long n    = (long)blockIdx.x * 4 + wq;
    float ws = 0.f;
    #pragma unroll
    for (int k = 0; k < KNB; ++k) ws += iw[n * KNB + k];
    const bool  zs  = (ws == 0.f);
    const float inv = zs ? (1.f / KNB) : (1.f / ws);
    float4 p = make_float4(0.f, 0.f, 0.f, 0.f);
    #pragma unroll 1
    for (int kb = 0; kb < KNB; kb += 8) {
        int idx[8]; float w[8];
        #pragma unroll
        for (int k = 0; k < 8; ++k) { idx[k] = nbr[n*KNB+kb+k]; w[k] = iw[n*KNB+kb+k]; }
        #pragma unroll
        for (int k = 0; k < 8; ++k) {
            const float  wk = zs ? inv : (w[k] * inv);
            const float4 f  = *(const float4*)(feat + (size_t)idx[k] * D + lane * 4);
            p.x += wk*f.x; p.y += wk*f.y; p.z += wk*f.z; p.w += wk*f.w;
        }
    }
    ushort4 o;
    o.x = f2bf(p.x); o.y = f2bf(p.y); o.z = f2bf(p.z); o.w = f2bf(p.w);
    *(ushort4*)(aggb + (size_t)n * 512 + lane * 4) = o;
}

// ---------------- K2: bf16 MFMA GEMM + LayerNorm, LDS-staged B ------------
// Block = 4 waves x 16 rows. B chunk (32 k x 256 n = 16 KB) double-buffered in
// LDS, shared by all 4 waves; one barrier per chunk. Staging hand-pipelined:
// global loads -> regs BEFORE the MFMA burst, ds_writes after, then barrier.
__global__ __launch_bounds__(256) void gemm_ln(const unsigned short* __restrict__ aggb,
                                               const unsigned short* __restrict__ wtp,
                                               const float* __restrict__ bias,
                                               const float* __restrict__ gamma,
                                               const float* __restrict__ beta,
                                               float* __restrict__ out) {
    __shared__ short sB[2][8192];                   // 2 x 16 KB B chunks
    __shared__ float fsh[4][4 * WSTR];              // 17.4 KB epilogue slabs

    const int t       = threadIdx.x;
    const int lane    = t & 63;
    const int wq      = t >> 6;
    const int quad    = lane >> 4;
    const int l15     = lane & 15;
    const int rowbase = blockIdx.x * 64 + wq * 16;

    const int arow = min(rowbase + l15, NN - 1);
    const unsigned short* aptr = aggb + (size_t)arow * 512 + quad * 8;
    const short8* wv = (const short8*)wtp;          // frag u of chunk kb: wv[kb*1024+u]

    // Prefetch all 8 A-frags (independent 16 B loads, issued up front).
    short8 aF[8];
    #pragma unroll
    for (int kb = 0; kb < 8; ++kb) aF[kb] = *(const short8*)(aptr + kb * 32);

    // Stage chunk 0.
    #pragma unroll
    for (int i = 0; i < 4; ++i)
        *(short8*)&sB[0][(size_t)(i * 256 + t) * 8] = wv[i * 256 + t];
    __syncthreads();

    f32x4 acc[16];
    #pragma unroll
    for (int c = 0; c < 16; ++c) acc[c] = (f32x4){0.f, 0.f, 0.f, 0.f};

    #pragma unroll
    for (int kb = 0; kb < 8; ++kb) {
        const int buf = kb & 1;
        short8 stg[4];
        if (kb < 7) {                               // issue next-chunk loads now
            #pragma unroll
            for (int i = 0; i < 4; ++i)
                stg[i] = wv[(size_t)(kb + 1) * 1024 + i * 256 + t];
        }
        #pragma unroll
        for (int c = 0; c < 16; ++c) {              // conflict-free ds_read_b128
            const short8 b = *(const short8*)&sB[buf][(size_t)(c * 64 + lane) * 8];
            acc[c] = __builtin_amdgcn_mfma_f32_16x16x32_bf16(aF[kb], b, acc[c], 0, 0, 0);
        }
        if (kb < 7) {                               // park next chunk in other buffer
            #pragma unroll
            for (int i = 0; i < 4; ++i)
                *(short8*)&sB[buf ^ 1][(size_t)(i * 256 + t) * 8] = stg[i];
        }
        __syncthreads();                            // one barrier per chunk
    }

    // Epilogue: +bias, LN, per-wave transpose slab, gamma/beta after
    // transpose (col = lane*4 -> 2 hoisted float4s), coalesced float4 stores.
    float bv[16];
    #pragma unroll
    for (int c = 0; c < 16; ++c) bv[c] = bias[c * 16 + l15];
    const float4 gv4 = *(const float4*)(gamma + lane * 4);
    const float4 bt4 = *(const float4*)(beta  + lane * 4);
    float* wsh = fsh[wq];

    #pragma unroll
    for (int j = 0; j < 4; ++j) {       // C/D: row = quad*4 + j, col = c*16 + l15
        float s = 0.f, sq = 0.f;
        #pragma unroll
        for (int c = 0; c < 16; ++c) {
            const float v = acc[c][j] + bv[c];
            s += v; sq += v * v;
        }
        #pragma unroll
        for (int off = 1; off < 16; off <<= 1) {   // reduce across l15 (same quad)
            s  += __shfl_xor(s,  off, 64);
            sq += __shfl_xor(sq, off, 64);
        }
        const float mean = s * (1.f / D);
        const float var  = sq * (1.f / D) - mean * mean;   // biased (torch LN)
        const float rstd = rsqrtf(var + 1e-5f);
        #pragma unroll
        for (int c = 0; c < 16; ++c)               // row quad*4+j -> slab slot quad
            wsh[quad * WSTR + c * 16 + l15] = (acc[c][j] + bv[c] - mean) * rstd;
        // same-wave LDS dependency: compiler inserts lgkmcnt wait, no barrier
        #pragma unroll
        for (int p = 0; p < 4; ++p) {              // rows {j, 4+j, 8+j, 12+j}
            const long  r  = rowbase + p * 4 + j;
            if (r < NN) {
                const float4 v = *(const float4*)(wsh + p * WSTR + lane * 4);
                float4 o;
                o.x = v.x * gv4.x + bt4.x; o.y = v.y * gv4.y + bt4.y;
                o.z = v.z * gv4.z + bt4.z; o.w = v.w * gv4.w + bt4.w;
                *(float4*)(out + r * D + lane * 4) = o;   // coalesced 1 KB/instr
            }
        }
    }
}

extern "C" void kernel_launch(void* const* d_in, const int* in_sizes, int n_in,
                              void* d_out, int out_size, void* d_ws, size_t ws_size,
                              hipStream_t stream) {
    const float* feat = (const float*)d_in[0];
    const int*   nbr  = (const int*)d_in[1];
    const float* iw   = (const float*)d_in[2];
    const float* Wm   = (const float*)d_in[3];
    const float* b    = (const float*)d_in[4];
    const float* g    = (const float*)d_in[5];
    const float* be   = (const float*)d_in[6];
    float*       out  = (float*)d_out;

    unsigned short* wtp   = (unsigned short*)d_ws;                   // 128 KB
    unsigned short* featb = (unsigned short*)((char*)d_ws + 131072); // 25.6 MB
    unsigned short* aggb  = (unsigned short*)d_out;                  // bf16 rows @ 1 KB

    const size_t need = 131072 + (size_t)NN * D * 2;

    if (ws_size >= need) {
        convert_all<<<dim3(6282), dim3(256), 0, stream>>>(feat, Wm, featb, wtp, 6250);
        pool_slices<<<dim3(8 * ((NN + NPB - 1) / NPB)), dim3(256), 0, stream>>>(
            featb, nbr, iw, aggb);
    } else {
        convert_all<<<dim3(32),   dim3(256), 0, stream>>>(feat, Wm, aggb, wtp, 0);
        pool_f     <<<dim3(NN / 4), dim3(256), 0, stream>>>(feat, nbr, iw, aggb);
    }
    gemm_ln<<<dim3((NN + 63) / 64), dim3(256), 0, stream>>>(aggb, wtp, b, g, be, out);
}

// Round 3
// 227.698 us; speedup vs baseline: 1.0251x; 1.0251x over previous
//
#include <hip/hip_runtime.h>

// ImportanceAggregator pipeline:
//   K0 convert_all  : feat fp32 -> featb bf16  AND  W -> wtp bf16, kb-major.
//   K1 pool_slices  : XCD-sliced gather. pool_b was at the per-XCD L2
//                     compulsory-fill floor (FETCH 174.8 MB = 8 x 22.1 MB).
//                     Block (chunk*8 + s) handles dims [s*32, s*32+32) only;
//                     with round-robin blockIdx%8 -> XCD dispatch, XCD s keeps
//                     its 3.2 MB featb slice L2-RESIDENT (< 4 MB L2) and the
//                     gathers hit L2. R2 failed (108 us) because MLP collapsed
//                     to 2 loads in flight per wave + serial 15-shuffle chain
//                     per node. R3 fix: batch 4 nodes -> 16 nt stream loads +
//                     8 gathers in flight (pool_b parity), THEN reduce.
//                     nt on nbr/iw/agg streams so they bypass L2 and don't
//                     evict the resident slice. Natural VGPR alloc (R7/R8).
//   K2 gemm_ln      : out = LN(agg @ W + b)*gamma + beta via MFMA 16x16x32,
//                     LDS-staged B double buffer (unchanged, proven).
// Lessons pinned: no 64-thread blocks (R6); no hoisted runtime-indexed arrays
// (R4 alloca->LDS); float4 epilogue beats segment stores (R3 vs R5);
// launch_bounds min-waves is a VGPR cap -> spill (R7); natural alloc (R8).
// agg bf16 rows live in d_out at 1 KB stride; gemm_ln blocks read only their
// own 64 rows then overwrite exactly those rows -> no cross-block hazard.
// Decision gate: if pool_slices dur >= 56 us or FETCH ~ 400 MB, slicing
// residency is refuted -> revert to pool_b.

#define NN   50000
#define KNB  16
#define D    256
#define WSTR 272   // epilogue slab stride (floats): 272%32=16 -> 2-way alias = free
#define NPB  32    // nodes per chunk in pool_slices (8 per wave)

typedef __attribute__((ext_vector_type(8))) short short8;   // 8 x bf16 (4 VGPRs)
typedef __attribute__((ext_vector_type(4))) float f32x4;
typedef __attribute__((ext_vector_type(4))) unsigned short us4;  // nt-capable

static __device__ __forceinline__ unsigned short f2bf(float x) {
    unsigned int u = __float_as_uint(x);
    return (unsigned short)((u + 0x7FFFu + ((u >> 16) & 1u)) >> 16);  // RNE
}
static __device__ __forceinline__ float bf2f(unsigned short h) {
    return __uint_as_float((unsigned int)h << 16);
}

// ---------------- K0: both conversions in one dispatch --------------------
// blocks [0,nfb): feat fp32 -> bf16 (8 elem/thread).
// blocks [nfb,nfb+32): W -> bf16 packed kb-major: frag g=(kb*16+c)*64+lane
//   holds B[k = kb*32 + (lane>>4)*8 + j][n = c*16 + (lane&15)], so chunk kb
//   is one contiguous 16 KB block (LDS-stageable with linear copies).
__global__ __launch_bounds__(256) void convert_all(const float* __restrict__ feat,
                                                   const float* __restrict__ Wm,
                                                   unsigned short* __restrict__ featb,
                                                   unsigned short* __restrict__ wtp,
                                                   int nfb) {
    if ((int)blockIdx.x < nfb) {
        const size_t g = (size_t)blockIdx.x * 256 + threadIdx.x;
        const float4 a = *(const float4*)(feat + g * 8);
        const float4 b = *(const float4*)(feat + g * 8 + 4);
        short8 o;
        o[0] = (short)f2bf(a.x); o[1] = (short)f2bf(a.y);
        o[2] = (short)f2bf(a.z); o[3] = (short)f2bf(a.w);
        o[4] = (short)f2bf(b.x); o[5] = (short)f2bf(b.y);
        o[6] = (short)f2bf(b.z); o[7] = (short)f2bf(b.w);
        *(short8*)(featb + g * 8) = o;
    } else {
        const int g    = (blockIdx.x - nfb) * 256 + threadIdx.x;    // 0..8191
        const int lane = g & 63;
        const int c    = (g >> 6) & 15;
        const int kb   = g >> 10;
        const int n    = c * 16 + (lane & 15);
        const int k0   = kb * 32 + (lane >> 4) * 8;
        short8 v;
        #pragma unroll
        for (int j = 0; j < 8; ++j) v[j] = (short)f2bf(Wm[(size_t)(k0 + j) * D + n]);
        *(short8*)(wtp + (size_t)g * 8) = v;
    }
}

// ---------------- K1: XCD-sliced weighted neighbor pooling ----------------
// Grid = 8 * ceil(NN/NPB); slice s = blockIdx&7 -> XCD s (round-robin).
// Wave = 8 nodes in two 4-node batches. Per batch: 16 nt stream loads, then
// 8 independent 64 B gathers (8 lanes x us4 per row), then per-node
// shfl_xor butterfly over k-groups (lane bits 3..5) and one 64 B nt store.
__global__ __launch_bounds__(256) void pool_slices(
        const unsigned short* __restrict__ featb,
        const int*   __restrict__ nbr,
        const float* __restrict__ iw,
        unsigned short* __restrict__ aggb) {
    const int t     = threadIdx.x;
    const int lane  = t & 63;
    const int wq    = t >> 6;
    const int s     = blockIdx.x & 7;            // slice == XCD (heuristic only)
    const int chunk = blockIdx.x >> 3;
    const int dl    = lane & 7;                  // dim-quad within 32-dim slice
    const int kg    = lane >> 3;                 // k-group 0..7
    const int dbase = s * 32 + dl * 4;           // short offset within a row

    const int n0 = chunk * NPB + wq * 8;         // 8 nodes per wave
    #pragma unroll 1
    for (int jj = 0; jj < 2; ++jj) {
        // ---- batch of 4 nodes: stream loads first (16 in flight) ----
        int   i0[4], i1[4];
        float w0[4], w1[4];
        #pragma unroll
        for (int j = 0; j < 4; ++j) {
            const int    n    = min(n0 + jj * 4 + j, NN - 1);   // clamp tail
            const size_t base = (size_t)n * KNB;
            i0[j] = __builtin_nontemporal_load(nbr + base + kg);
            i1[j] = __builtin_nontemporal_load(nbr + base + 8 + kg);
            w0[j] = __builtin_nontemporal_load(iw  + base + kg);
            w1[j] = __builtin_nontemporal_load(iw  + base + 8 + kg);
        }
        // ---- 8 independent gathers in flight (L2-resident slice) ----
        us4 u0[4], u1[4];
        #pragma unroll
        for (int j = 0; j < 4; ++j) {
            u0[j] = *(const us4*)(featb + (size_t)i0[j] * D + dbase);
            u1[j] = *(const us4*)(featb + (size_t)i1[j] * D + dbase);
        }
        // ---- reductions + stores ----
        #pragma unroll
        for (int j = 0; j < 4; ++j) {
            float ws = w0[j] + w1[j];            // sum over 16 k via lane bits 3..5
            ws += __shfl_xor(ws, 8,  64);
            ws += __shfl_xor(ws, 16, 64);
            ws += __shfl_xor(ws, 32, 64);
            const bool  zsum = (ws == 0.f);
            const float inv  = zsum ? (1.f / KNB) : (1.f / ws);
            const float f0   = zsum ? inv : (w0[j] * inv);
            const float f1   = zsum ? inv : (w1[j] * inv);
            float4 p;
            p.x = f0 * bf2f(u0[j][0]) + f1 * bf2f(u1[j][0]);
            p.y = f0 * bf2f(u0[j][1]) + f1 * bf2f(u1[j][1]);
            p.z = f0 * bf2f(u0[j][2]) + f1 * bf2f(u1[j][2]);
            p.w = f0 * bf2f(u0[j][3]) + f1 * bf2f(u1[j][3]);
            #pragma unroll
            for (int off = 8; off < 64; off <<= 1) {
                p.x += __shfl_xor(p.x, off, 64);
                p.y += __shfl_xor(p.y, off, 64);
                p.z += __shfl_xor(p.z, off, 64);
                p.w += __shfl_xor(p.w, off, 64);
            }
            const int n = n0 + jj * 4 + j;
            if (kg == 0 && n < NN) {             // lanes 0..7: one 64 B line
                us4 o;
                o[0] = f2bf(p.x); o[1] = f2bf(p.y);
                o[2] = f2bf(p.z); o[3] = f2bf(p.w);
                __builtin_nontemporal_store(o,
                    (us4*)(aggb + (size_t)n * 512 + dbase));
            }
        }
    }
}

// Fallback (ws too small for featb): fp32 gathers, one wave per node.
__global__ __launch_bounds__(256, 8) void pool_f(const float* __restrict__ feat,
                                                 const int*   __restrict__ nbr,
                                                 const float* __restrict__ iw,
                                                 unsigned short* __restrict__ aggb) {
    const int  t    = threadIdx.x;
    const int  lane = t & 63;
    const int  wq   = t >> 6;
    const long n    = (long)blockIdx.x * 4 + wq;
    float ws = 0.f;
    #pragma unroll
    for (int k = 0; k < KNB; ++k) ws += iw[n * KNB + k];
    const bool  zs  = (ws == 0.f);
    const float inv = zs ? (1.f / KNB) : (1.f / ws);
    float4 p = make_float4(0.f, 0.f, 0.f, 0.f);
    #pragma unroll 1
    for (int kb = 0; kb < KNB; kb += 8) {
        int idx[8]; float w[8];
        #pragma unroll
        for (int k = 0; k < 8; ++k) { idx[k] = nbr[n*KNB+kb+k]; w[k] = iw[n*KNB+kb+k]; }
        #pragma unroll
        for (int k = 0; k < 8; ++k) {
            const float  wk = zs ? inv : (w[k] * inv);
            const float4 f  = *(const float4*)(feat + (size_t)idx[k] * D + lane * 4);
            p.x += wk*f.x; p.y += wk*f.y; p.z += wk*f.z; p.w += wk*f.w;
        }
    }
    ushort4 o;
    o.x = f2bf(p.x); o.y = f2bf(p.y); o.z = f2bf(p.z); o.w = f2bf(p.w);
    *(ushort4*)(aggb + (size_t)n * 512 + lane * 4) = o;
}

// ---------------- K2: bf16 MFMA GEMM + LayerNorm, LDS-staged B ------------
// Block = 4 waves x 16 rows. B chunk (32 k x 256 n = 16 KB) double-buffered in
// LDS, shared by all 4 waves; one barrier per chunk. Staging hand-pipelined:
// global loads -> regs BEFORE the MFMA burst, ds_writes after, then barrier.
__global__ __launch_bounds__(256) void gemm_ln(const unsigned short* __restrict__ aggb,
                                               const unsigned short* __restrict__ wtp,
                                               const float* __restrict__ bias,
                                               const float* __restrict__ gamma,
                                               const float* __restrict__ beta,
                                               float* __restrict__ out) {
    __shared__ short sB[2][8192];                   // 2 x 16 KB B chunks
    __shared__ float fsh[4][4 * WSTR];              // 17.4 KB epilogue slabs

    const int t       = threadIdx.x;
    const int lane    = t & 63;
    const int wq      = t >> 6;
    const int quad    = lane >> 4;
    const int l15     = lane & 15;
    const int rowbase = blockIdx.x * 64 + wq * 16;

    const int arow = min(rowbase + l15, NN - 1);
    const unsigned short* aptr = aggb + (size_t)arow * 512 + quad * 8;
    const short8* wv = (const short8*)wtp;          // frag u of chunk kb: wv[kb*1024+u]

    // Prefetch all 8 A-frags (independent 16 B loads, issued up front).
    short8 aF[8];
    #pragma unroll
    for (int kb = 0; kb < 8; ++kb) aF[kb] = *(const short8*)(aptr + kb * 32);

    // Stage chunk 0.
    #pragma unroll
    for (int i = 0; i < 4; ++i)
        *(short8*)&sB[0][(size_t)(i * 256 + t) * 8] = wv[i * 256 + t];
    __syncthreads();

    f32x4 acc[16];
    #pragma unroll
    for (int c = 0; c < 16; ++c) acc[c] = (f32x4){0.f, 0.f, 0.f, 0.f};

    #pragma unroll
    for (int kb = 0; kb < 8; ++kb) {
        const int buf = kb & 1;
        short8 stg[4];
        if (kb < 7) {                               // issue next-chunk loads now
            #pragma unroll
            for (int i = 0; i < 4; ++i)
                stg[i] = wv[(size_t)(kb + 1) * 1024 + i * 256 + t];
        }
        #pragma unroll
        for (int c = 0; c < 16; ++c) {              // conflict-free ds_read_b128
            const short8 b = *(const short8*)&sB[buf][(size_t)(c * 64 + lane) * 8];
            acc[c] = __builtin_amdgcn_mfma_f32_16x16x32_bf16(aF[kb], b, acc[c], 0, 0, 0);
        }
        if (kb < 7) {                               // park next chunk in other buffer
            #pragma unroll
            for (int i = 0; i < 4; ++i)
                *(short8*)&sB[buf ^ 1][(size_t)(i * 256 + t) * 8] = stg[i];
        }
        __syncthreads();                            // one barrier per chunk
    }

    // Epilogue: +bias, LN, per-wave transpose slab, gamma/beta after
    // transpose (col = lane*4 -> 2 hoisted float4s), coalesced float4 stores.
    float bv[16];
    #pragma unroll
    for (int c = 0; c < 16; ++c) bv[c] = bias[c * 16 + l15];
    const float4 gv4 = *(const float4*)(gamma + lane * 4);
    const float4 bt4 = *(const float4*)(beta  + lane * 4);
    float* wsh = fsh[wq];

    #pragma unroll
    for (int j = 0; j < 4; ++j) {       // C/D: row = quad*4 + j, col = c*16 + l15
        float s = 0.f, sq = 0.f;
        #pragma unroll
        for (int c = 0; c < 16; ++c) {
            const float v = acc[c][j] + bv[c];
            s += v; sq += v * v;
        }
        #pragma unroll
        for (int off = 1; off < 16; off <<= 1) {   // reduce across l15 (same quad)
            s  += __shfl_xor(s,  off, 64);
            sq += __shfl_xor(sq, off, 64);
        }
        const float mean = s * (1.f / D);
        const float var  = sq * (1.f / D) - mean * mean;   // biased (torch LN)
        const float rstd = rsqrtf(var + 1e-5f);
        #pragma unroll
        for (int c = 0; c < 16; ++c)               // row quad*4+j -> slab slot quad
            wsh[quad * WSTR + c * 16 + l15] = (acc[c][j] + bv[c] - mean) * rstd;
        // same-wave LDS dependency: compiler inserts lgkmcnt wait, no barrier
        #pragma unroll
        for (int p = 0; p < 4; ++p) {              // rows {j, 4+j, 8+j, 12+j}
            const long  r  = rowbase + p * 4 + j;
            if (r < NN) {
                const float4 v = *(const float4*)(wsh + p * WSTR + lane * 4);
                float4 o;
                o.x = v.x * gv4.x + bt4.x; o.y = v.y * gv4.y + bt4.y;
                o.z = v.z * gv4.z + bt4.z; o.w = v.w * gv4.w + bt4.w;
                *(float4*)(out + r * D + lane * 4) = o;   // coalesced 1 KB/instr
            }
        }
    }
}

extern "C" void kernel_launch(void* const* d_in, const int* in_sizes, int n_in,
                              void* d_out, int out_size, void* d_ws, size_t ws_size,
                              hipStream_t stream) {
    const float* feat = (const float*)d_in[0];
    const int*   nbr  = (const int*)d_in[1];
    const float* iw   = (const float*)d_in[2];
    const float* Wm   = (const float*)d_in[3];
    const float* b    = (const float*)d_in[4];
    const float* g    = (const float*)d_in[5];
    const float* be   = (const float*)d_in[6];
    float*       out  = (float*)d_out;

    unsigned short* wtp   = (unsigned short*)d_ws;                   // 128 KB
    unsigned short* featb = (unsigned short*)((char*)d_ws + 131072); // 25.6 MB
    unsigned short* aggb  = (unsigned short*)d_out;                  // bf16 rows @ 1 KB

    const size_t need = 131072 + (size_t)NN * D * 2;

    if (ws_size >= need) {
        convert_all<<<dim3(6282), dim3(256), 0, stream>>>(feat, Wm, featb, wtp, 6250);
        pool_slices<<<dim3(8 * ((NN + NPB - 1) / NPB)), dim3(256), 0, stream>>>(
            featb, nbr, iw, aggb);
    } else {
        convert_all<<<dim3(32),   dim3(256), 0, stream>>>(feat, Wm, aggb, wtp, 0);
        pool_f     <<<dim3(NN / 4), dim3(256), 0, stream>>>(feat, nbr, iw, aggb);
    }
    gemm_ln<<<dim3((NN + 63) / 64), dim3(256), 0, stream>>>(aggb, wtp, b, g, be, out);
}

// Round 5
// 191.309 us; speedup vs baseline: 1.2201x; 1.1902x over previous
//
#include <hip/hip_runtime.h>

// ImportanceAggregator pipeline:
//   K0 convert_all  : feat fp32 -> featb bf16 (slice-major [8][NN][32] when
//                     slicemaj=1, row-major otherwise) and W -> wtp bf16.
//   K1 pool_sg      : XCD-sliced gather. pool_b floor = per-XCD L2 fill
//                     (FETCH 174.8 MB @ ~3.6 TB/s). Slice-contiguous featb
//                     (3.2 MB/XCD < 4 MB L2) + blockIdx%8 -> XCD round-robin
//                     keeps each XCD's slice L2-resident. Wave = 8 nodes x
//                     8 lanes; coalesced nt row-loads, shfl broadcast,
//                     16 independent 64 B gathers in flight, no out shuffles.
//   K2 gemm_ln      : out = LN(agg @ W + b)*gamma + beta via MFMA 16x16x32,
//                     LDS-staged B double buffer (unchanged, proven).
// R4 LESSON (rigor): aggb scratch MUST NOT live in d_out. Replay-poison of
// d_out raced our pool-write->gemm-read chain: first check passed, replayed
// graph diverged, fresh launch correct. aggb now lives in d_ws (astr=256);
// d_out is write-only. Fallback tiers keep the proven R0 path (pool_b,
// aggb=d_out astr=512) when ws is too small for the extra 25.6 MB.
// Lessons pinned: no 64-thread blocks (R6); no hoisted runtime-indexed arrays
// (R4 alloca->LDS); float4 epilogue beats segment stores (R3 vs R5);
// launch_bounds min-waves is a VGPR cap -> spill (R7); natural alloc (R8);
// nt builtins need ext_vector types (R1); >=8 loads in flight per wave (R2);
// interleaved slices share 128 B lines -> 6.4 MB/XCD, thrash (R3).
// Gate: if pool_sg FETCH >= 150 MB, residency is refuted -> revert pool_b.

#define NN   50000
#define KNB  16
#define D    256
#define WSTR 272   // epilogue slab stride (floats): 272%32=16 -> 2-way alias = free

typedef __attribute__((ext_vector_type(8))) short short8;   // 8 x bf16 (4 VGPRs)
typedef __attribute__((ext_vector_type(4))) float f32x4;
typedef __attribute__((ext_vector_type(4))) unsigned short us4;  // nt-capable
typedef __attribute__((ext_vector_type(2))) int   i32x2;
typedef __attribute__((ext_vector_type(2))) float f32x2;

static __device__ __forceinline__ unsigned short f2bf(float x) {
    unsigned int u = __float_as_uint(x);
    return (unsigned short)((u + 0x7FFFu + ((u >> 16) & 1u)) >> 16);  // RNE
}
static __device__ __forceinline__ float bf2f(unsigned short h) {
    return __uint_as_float((unsigned int)h << 16);
}

// ---------------- K0: both conversions in one dispatch --------------------
// blocks [0,nfb): feat fp32 -> featb bf16. slicemaj=1: slice-major, addr =
//   s*(NN*32) + n*32 + d  (slice s = dims [s*32,s*32+32) of all rows, one
//   contiguous 3.2 MB block). slicemaj=0: row-major (R0 layout).
// blocks [nfb,nfb+32): W -> bf16 packed kb-major: frag g=(kb*16+c)*64+lane
//   holds B[k = kb*32 + (lane>>4)*8 + j][n = c*16 + (lane&15)].
__global__ __launch_bounds__(256) void convert_all(const float* __restrict__ feat,
                                                   const float* __restrict__ Wm,
                                                   unsigned short* __restrict__ featb,
                                                   unsigned short* __restrict__ wtp,
                                                   int nfb, int slicemaj) {
    if ((int)blockIdx.x < nfb) {
        const size_t g = (size_t)blockIdx.x * 256 + threadIdx.x;
        const float4 a = *(const float4*)(feat + g * 8);
        const float4 b = *(const float4*)(feat + g * 8 + 4);
        short8 o;
        o[0] = (short)f2bf(a.x); o[1] = (short)f2bf(a.y);
        o[2] = (short)f2bf(a.z); o[3] = (short)f2bf(a.w);
        o[4] = (short)f2bf(b.x); o[5] = (short)f2bf(b.y);
        o[6] = (short)f2bf(b.z); o[7] = (short)f2bf(b.w);
        if (slicemaj) {
            const int n  = (int)(g >> 5);            // row
            const int s  = ((int)g >> 2) & 7;        // slice
            const int d0 = ((int)g & 3) * 8;         // dim offset within slice
            *(short8*)(featb + (size_t)s * ((size_t)NN * 32)
                             + (size_t)n * 32 + d0) = o;
        } else {
            *(short8*)(featb + g * 8) = o;
        }
    } else {
        const int g    = (blockIdx.x - nfb) * 256 + threadIdx.x;    // 0..8191
        const int lane = g & 63;
        const int c    = (g >> 6) & 15;
        const int kb   = g >> 10;
        const int n    = c * 16 + (lane & 15);
        const int k0   = kb * 32 + (lane >> 4) * 8;
        short8 v;
        #pragma unroll
        for (int j = 0; j < 8; ++j) v[j] = (short)f2bf(Wm[(size_t)(k0 + j) * D + n]);
        *(short8*)(wtp + (size_t)g * 8) = v;
    }
}

// ---------------- K1: XCD-sliced weighted neighbor pooling ----------------
// Grid = 8 * ceil(NN/32); slice s = blockIdx&7 -> XCD s (round-robin).
// Wave = 8 nodes (nd = lane>>3) x 8 dim-quads (dl = lane&7). Per wave:
//   1 x int2 nt-load  : nbr rows of all 8 nodes (512 B coalesced)
//   1 x float2 nt-load: iw rows (512 B coalesced)
//   3 shfl_xor        : wsum per node within its 8-lane group
//   16 x { shfl idx/w broadcast; independent 64 B gather; 4 FMA }
//   1 x 8 B nt-store per lane -> agg row n dims [s*32+dl*4, +4)
// featb slice s is contiguous (3.2 MB) -> resident in XCD s's 4 MB L2.
__global__ __launch_bounds__(256) void pool_sg(
        const unsigned short* __restrict__ featb,   // [8][NN][32] slice-major
        const int*   __restrict__ nbr,
        const float* __restrict__ iw,
        unsigned short* __restrict__ aggb, int astr) {
    const int t     = threadIdx.x;
    const int lane  = t & 63;
    const int wq    = t >> 6;
    const int s     = blockIdx.x & 7;            // slice == XCD (heuristic only)
    const int chunk = blockIdx.x >> 3;
    const int nd    = lane >> 3;                 // node within wave 0..7
    const int dl    = lane & 7;                  // dim-quad within 64 B slice
    const int n     = chunk * 32 + wq * 8 + nd;
    const int nc    = min(n, NN - 1);            // clamp tail (stores guarded)
    const unsigned short* fs = featb + (size_t)s * ((size_t)NN * 32);

    // Coalesced row loads: lane dl holds entries {2dl, 2dl+1} of node nd.
    const i32x2 i2 = __builtin_nontemporal_load(
        (const i32x2*)(nbr + (size_t)nc * KNB + dl * 2));
    const f32x2 w2 = __builtin_nontemporal_load(
        (const f32x2*)(iw  + (size_t)nc * KNB + dl * 2));

    // wsum over the node's 16 weights: pair-sum + 3-step butterfly in-group.
    float ws = w2[0] + w2[1];
    ws += __shfl_xor(ws, 1, 64);
    ws += __shfl_xor(ws, 2, 64);
    ws += __shfl_xor(ws, 4, 64);
    const bool  zs  = (ws == 0.f);
    const float inv = zs ? (1.f / KNB) : (1.f / ws);
    f32x2 wn;                                    // pre-scaled weights
    wn[0] = zs ? inv : w2[0] * inv;
    wn[1] = zs ? inv : w2[1] * inv;

    float4 p = make_float4(0.f, 0.f, 0.f, 0.f);
    const int sbase = nd * 8;
    #pragma unroll
    for (int k = 0; k < KNB; ++k) {              // 16 independent gathers
        const int   src = sbase + (k >> 1);
        const int   ik  = __shfl((k & 1) ? i2[1] : i2[0], src, 64);
        const float wk  = __shfl((k & 1) ? wn[1] : wn[0], src, 64);
        const us4   u   = *(const us4*)(fs + (size_t)(unsigned)ik * 32 + dl * 4);
        p.x += wk * bf2f(u[0]);
        p.y += wk * bf2f(u[1]);
        p.z += wk * bf2f(u[2]);
        p.w += wk * bf2f(u[3]);
    }
    if (n < NN) {                                // agg row n, dims s*32+dl*4
        us4 o;
        o[0] = f2bf(p.x); o[1] = f2bf(p.y); o[2] = f2bf(p.z); o[3] = f2bf(p.w);
        __builtin_nontemporal_store(o,
            (us4*)(aggb + (size_t)n * astr + s * 32 + dl * 4));
    }
}

// ---------------- pool_b: proven R0 gather (row-major featb) --------------
__global__ __launch_bounds__(256, 8) void pool_b(const unsigned short* __restrict__ featb,
                                                 const int*   __restrict__ nbr,
                                                 const float* __restrict__ iw,
                                                 unsigned short* __restrict__ aggb,
                                                 int astr) {
    const int  t    = threadIdx.x;
    const int  lane = t & 63;
    const int  wq   = t >> 6;
    const long n    = (long)blockIdx.x * 4 + wq;   // one wave per node

    float ws = 0.f;
    #pragma unroll
    for (int k = 0; k < KNB; ++k) ws += iw[n * KNB + k];
    const bool  zs  = (ws == 0.f);
    const float inv = zs ? (1.f / KNB) : (1.f / ws);

    float4 p = make_float4(0.f, 0.f, 0.f, 0.f);
    #pragma unroll 1
    for (int kb = 0; kb < KNB; kb += 8) {          // 8 gathers in flight
        int   idx[8];
        float w[8];
        #pragma unroll
        for (int k = 0; k < 8; ++k) {
            idx[k] = nbr[n * KNB + kb + k];
            w[k]   = iw [n * KNB + kb + k];
        }
        #pragma unroll
        for (int k = 0; k < 8; ++k) {
            const float   wk = zs ? inv : (w[k] * inv);
            const ushort4 u  = *(const ushort4*)(featb + (size_t)idx[k] * D + lane * 4);
            p.x += wk * bf2f(u.x); p.y += wk * bf2f(u.y);
            p.z += wk * bf2f(u.z); p.w += wk * bf2f(u.w);
        }
    }
    ushort4 o;
    o.x = f2bf(p.x); o.y = f2bf(p.y); o.z = f2bf(p.z); o.w = f2bf(p.w);
    *(ushort4*)(aggb + (size_t)n * astr + lane * 4) = o;
}

// Fallback (ws too small for featb): fp32 gathers, one wave per node.
__global__ __launch_bounds__(256, 8) void pool_f(const float* __restrict__ feat,
                                                 const int*   __restrict__ nbr,
                                                 const float* __restrict__ iw,
                                                 unsigned short* __restrict__ aggb,
                                                 int astr) {
    const int  t    = threadIdx.x;
    const int  lane = t & 63;
    const int  wq   = t >> 6;
    const long n    = (long)blockIdx.x * 4 + wq;
    float ws = 0.f;
    #pragma unroll
    for (int k = 0; k < KNB; ++k) ws += iw[n * KNB + k];
    const bool  zs  = (ws == 0.f);
    const float inv = zs ? (1.f / KNB) : (1.f / ws);
    float4 p = make_float4(0.f, 0.f, 0.f, 0.f);
    #pragma unroll 1
    for (int kb = 0; kb < KNB; kb += 8) {
        int idx[8]; float w[8];
        #pragma unroll
        for (int k = 0; k < 8; ++k) { idx[k] = nbr[n*KNB+kb+k]; w[k] = iw[n*KNB+kb+k]; }
        #pragma unroll
        for (int k = 0; k < 8; ++k) {
            const float  wk = zs ? inv : (w[k] * inv);
            const float4 f  = *(const float4*)(feat + (size_t)idx[k] * D + lane * 4);
            p.x += wk*f.x; p.y += wk*f.y; p.z += wk*f.z; p.w += wk*f.w;
        }
    }
    ushort4 o;
    o.x = f2bf(p.x); o.y = f2bf(p.y); o.z = f2bf(p.z); o.w = f2bf(p.w);
    *(ushort4*)(aggb + (size_t)n * astr + lane * 4) = o;
}

// ---------------- K2: bf16 MFMA GEMM + LayerNorm, LDS-staged B ------------
// Block = 4 waves x 16 rows. B chunk (32 k x 256 n = 16 KB) double-buffered in
// LDS, shared by all 4 waves; one barrier per chunk. Staging hand-pipelined:
// global loads -> regs BEFORE the MFMA burst, ds_writes after, then barrier.
__global__ __launch_bounds__(256) void gemm_ln(const unsigned short* __restrict__ aggb,
                                               int astr,
                                               const unsigned short* __restrict__ wtp,
                                               const float* __restrict__ bias,
                                               const float* __restrict__ gamma,
                                               const float* __restrict__ beta,
                                               float* __restrict__ out) {
    __shared__ short sB[2][8192];                   // 2 x 16 KB B chunks
    __shared__ float fsh[4][4 * WSTR];              // 17.4 KB epilogue slabs

    const int t       = threadIdx.x;
    const int lane    = t & 63;
    const int wq      = t >> 6;
    const int quad    = lane >> 4;
    const int l15     = lane & 15;
    const int rowbase = blockIdx.x * 64 + wq * 16;

    const int arow = min(rowbase + l15, NN - 1);
    const unsigned short* aptr = aggb + (size_t)arow * astr + quad * 8;
    const short8* wv = (const short8*)wtp;          // frag u of chunk kb: wv[kb*1024+u]

    // Prefetch all 8 A-frags (independent 16 B loads, issued up front).
    short8 aF[8];
    #pragma unroll
    for (int kb = 0; kb < 8; ++kb) aF[kb] = *(const short8*)(aptr + kb * 32);

    // Stage chunk 0.
    #pragma unroll
    for (int i = 0; i < 4; ++i)
        *(short8*)&sB[0][(size_t)(i * 256 + t) * 8] = wv[i * 256 + t];
    __syncthreads();

    f32x4 acc[16];
    #pragma unroll
    for (int c = 0; c < 16; ++c) acc[c] = (f32x4){0.f, 0.f, 0.f, 0.f};

    #pragma unroll
    for (int kb = 0; kb < 8; ++kb) {
        const int buf = kb & 1;
        short8 stg[4];
        if (kb < 7) {                               // issue next-chunk loads now
            #pragma unroll
            for (int i = 0; i < 4; ++i)
                stg[i] = wv[(size_t)(kb + 1) * 1024 + i * 256 + t];
        }
        #pragma unroll
        for (int c = 0; c < 16; ++c) {              // conflict-free ds_read_b128
            const short8 b = *(const short8*)&sB[buf][(size_t)(c * 64 + lane) * 8];
            acc[c] = __builtin_amdgcn_mfma_f32_16x16x32_bf16(aF[kb], b, acc[c], 0, 0, 0);
        }
        if (kb < 7) {                               // park next chunk in other buffer
            #pragma unroll
            for (int i = 0; i < 4; ++i)
                *(short8*)&sB[buf ^ 1][(size_t)(i * 256 + t) * 8] = stg[i];
        }
        __syncthreads();                            // one barrier per chunk
    }

    // Epilogue: +bias, LN, per-wave transpose slab, gamma/beta after
    // transpose (col = lane*4 -> 2 hoisted float4s), coalesced float4 stores.
    float bv[16];
    #pragma unroll
    for (int c = 0; c < 16; ++c) bv[c] = bias[c * 16 + l15];
    const float4 gv4 = *(const float4*)(gamma + lane * 4);
    const float4 bt4 = *(const float4*)(beta  + lane * 4);
    float* wsh = fsh[wq];

    #pragma unroll
    for (int j = 0; j < 4; ++j) {       // C/D: row = quad*4 + j, col = c*16 + l15
        float s = 0.f, sq = 0.f;
        #pragma unroll
        for (int c = 0; c < 16; ++c) {
            const float v = acc[c][j] + bv[c];
            s += v; sq += v * v;
        }
        #pragma unroll
        for (int off = 1; off < 16; off <<= 1) {   // reduce across l15 (same quad)
            s  += __shfl_xor(s,  off, 64);
            sq += __shfl_xor(sq, off, 64);
        }
        const float mean = s * (1.f / D);
        const float var  = sq * (1.f / D) - mean * mean;   // biased (torch LN)
        const float rstd = rsqrtf(var + 1e-5f);
        #pragma unroll
        for (int c = 0; c < 16; ++c)               // row quad*4+j -> slab slot quad
            wsh[quad * WSTR + c * 16 + l15] = (acc[c][j] + bv[c] - mean) * rstd;
        // same-wave LDS dependency: compiler inserts lgkmcnt wait, no barrier
        #pragma unroll
        for (int p = 0; p < 4; ++p) {              // rows {j, 4+j, 8+j, 12+j}
            const long  r  = rowbase + p * 4 + j;
            if (r < NN) {
                const float4 v = *(const float4*)(wsh + p * WSTR + lane * 4);
                float4 o;
                o.x = v.x * gv4.x + bt4.x; o.y = v.y * gv4.y + bt4.y;
                o.z = v.z * gv4.z + bt4.z; o.w = v.w * gv4.w + bt4.w;
                *(float4*)(out + r * D + lane * 4) = o;   // coalesced 1 KB/instr
            }
        }
    }
}

extern "C" void kernel_launch(void* const* d_in, const int* in_sizes, int n_in,
                              void* d_out, int out_size, void* d_ws, size_t ws_size,
                              hipStream_t stream) {
    const float* feat = (const float*)d_in[0];
    const int*   nbr  = (const int*)d_in[1];
    const float* iw   = (const float*)d_in[2];
    const float* Wm   = (const float*)d_in[3];
    const float* b    = (const float*)d_in[4];
    const float* g    = (const float*)d_in[5];
    const float* be   = (const float*)d_in[6];
    float*       out  = (float*)d_out;

    const size_t featB = (size_t)NN * D * 2;                         // 25.6 MB
    unsigned short* wtp    = (unsigned short*)d_ws;                  // 128 KB
    unsigned short* featb  = (unsigned short*)((char*)d_ws + 131072);
    unsigned short* aggb_w = (unsigned short*)((char*)d_ws + 131072 + featB);

    if (ws_size >= 131072 + 2 * featB) {
        // Full path: slice-major featb, XCD-sliced pool, aggb in d_ws.
        // d_out is WRITE-ONLY (R4 lesson: replay-poison races d_out scratch).
        convert_all<<<dim3(6282), dim3(256), 0, stream>>>(feat, Wm, featb, wtp,
                                                          6250, 1);
        pool_sg<<<dim3(8 * ((NN + 31) / 32)), dim3(256), 0, stream>>>(
            featb, nbr, iw, aggb_w, 256);
        gemm_ln<<<dim3((NN + 63) / 64), dim3(256), 0, stream>>>(
            aggb_w, 256, wtp, b, g, be, out);
    } else if (ws_size >= 131072 + featB) {
        // Proven R0 path: row-major featb, pool_b, aggb aliases d_out.
        unsigned short* aggb = (unsigned short*)d_out;
        convert_all<<<dim3(6282), dim3(256), 0, stream>>>(feat, Wm, featb, wtp,
                                                          6250, 0);
        pool_b<<<dim3(NN / 4), dim3(256), 0, stream>>>(featb, nbr, iw, aggb, 512);
        gemm_ln<<<dim3((NN + 63) / 64), dim3(256), 0, stream>>>(
            aggb, 512, wtp, b, g, be, out);
    } else {
        unsigned short* aggb = (unsigned short*)d_out;
        convert_all<<<dim3(32), dim3(256), 0, stream>>>(feat, Wm, featb, wtp, 0, 0);
        pool_f<<<dim3(NN / 4), dim3(256), 0, stream>>>(feat, nbr, iw, aggb, 512);
        gemm_ln<<<dim3((NN + 63) / 64), dim3(256), 0, stream>>>(
            aggb, 512, wtp, b, g, be, out);
    }
}